// Round 1
// baseline (442.635 us; speedup 1.0000x reference)
//
#include <hip/hip_runtime.h>
#include <math.h>

#define N_ 30000
#define K_ 15
#define T_ 400
#define NC_ 5

static constexpr float TWO_PI_F = 6.283185307179586f;
static constexpr float SMOOTH_F = 0.2f;

// ---------------- Pass A: emd_signals[n][t] = sum_c emd_seasonal[n][c][t] ----
__global__ __launch_bounds__(256) void emd_sum_kernel(
    const float* __restrict__ emd, float* __restrict__ out) {
  int g = blockIdx.x * blockDim.x + threadIdx.x;          // over N_*(T_/4)
  if (g >= N_ * (T_ / 4)) return;
  int n = g / (T_ / 4);
  int j = g - n * (T_ / 4);
  const float4* row = (const float4*)(emd + (size_t)n * 4 * T_);
  float4 a = row[j];
  float4 b = row[j + (T_ / 4)];
  float4 c = row[j + 2 * (T_ / 4)];
  float4 d = row[j + 3 * (T_ / 4)];
  float4 s;
  s.x = a.x + b.x + c.x + d.x;
  s.y = a.y + b.y + c.y + d.y;
  s.z = a.z + b.z + c.z + d.z;
  s.w = a.w + b.w + c.w + d.w;
  ((float4*)out)[g] = s;
}

// ---------------- Pass B: smoothed residual amplitudes/phases ----------------
__global__ __launch_bounds__(256) void params_kernel(
    const int* __restrict__ idx, const float* __restrict__ nw,
    const float* __restrict__ amps, const float* __restrict__ phases,
    float* __restrict__ amp_s_out, float* __restrict__ ph_s_out) {
  int n = blockIdx.x * blockDim.x + threadIdx.x;
  if (n >= N_) return;
  int id[K_];
  float w[K_];
#pragma unroll
  for (int k = 0; k < K_; k++) {
    id[k] = idx[n * K_ + k];
    w[k] = nw[n * K_ + k];
  }
#pragma unroll
  for (int c = 0; c < NC_; c++) {
    float asum = 0.f, ssum = 0.f, csum = 0.f;
#pragma unroll
    for (int k = 0; k < K_; k++) {
      float a = amps[id[k] * NC_ + c];
      float p = phases[id[k] * NC_ + c];
      asum += w[k] * a;
      ssum += w[k] * __sinf(p);
      csum += w[k] * __cosf(p);
    }
    float amp_s = (1.f - SMOOTH_F) * amps[n * NC_ + c] + SMOOTH_F * asum;
    float pavg = atan2f(ssum, csum);
    float ph_s = (1.f - SMOOTH_F) * phases[n * NC_ + c] + SMOOTH_F * pavg;
    amp_s_out[n * NC_ + c] = amp_s;
    ph_s_out[n * NC_ + c] = ph_s;
  }
}

// ---------------- Pass C: gather + blend + residual harmonics ----------------
__global__ __launch_bounds__(256) void main_kernel(
    const float* __restrict__ emd_sig, const float* __restrict__ tvec,
    const int* __restrict__ idx, const float* __restrict__ nw,
    const float* __restrict__ lw, const float* __restrict__ offset,
    const float* __restrict__ trend, const float* __restrict__ esw,
    const float* __restrict__ lsw, const float* __restrict__ amp_s,
    const float* __restrict__ ph_s, const float* __restrict__ periods,
    float* __restrict__ out) {
  int n = blockIdx.x;
  int tid = threadIdx.x;
  __shared__ int sidx[K_];
  __shared__ float snw[K_], slw[K_];
  __shared__ float samp[NC_], sph[NC_], somega[NC_];
  __shared__ float s_off, s_tr, s_ew, s_lw;
  if (tid < K_) {
    sidx[tid] = idx[n * K_ + tid];
    snw[tid] = nw[n * K_ + tid];
    slw[tid] = lw[n * K_ + tid];
  } else if (tid >= 32 && tid < 32 + NC_) {
    int c = tid - 32;
    samp[c] = amp_s[n * NC_ + c];
    sph[c] = ph_s[n * NC_ + c];
    float per = fminf(fmaxf(periods[c], 15.f), 350.f);
    somega[c] = TWO_PI_F / per;
  } else if (tid == 64) {
    s_off = offset[n];
    s_tr = trend[n];
    s_ew = 1.f / (1.f + __expf(-esw[n]));
    s_lw = 1.f / (1.f + __expf(-lsw[n]));
  }
  __syncthreads();
  float ew = s_ew, lww = s_lw;
  for (int t = tid; t < T_; t += 256) {
    float own = emd_sig[(size_t)n * T_ + t];
    float lsum = 0.f, rsum = 0.f;
#pragma unroll
    for (int k = 0; k < K_; k++) {
      float v = emd_sig[(size_t)sidx[k] * T_ + t];
      lsum += slw[k] * v;
      rsum += snw[k] * v;
    }
    float adjusted = (1.f - ew) * own + ew * lww * lsum + ew * (1.f - lww) * rsum;
    float tf = tvec[t];
    float res = 0.f;
#pragma unroll
    for (int c = 0; c < NC_; c++) res += samp[c] * __sinf(somega[c] * tf + sph[c]);
    out[(size_t)n * T_ + t] = s_off + s_tr * tf + adjusted + res;
  }
}

// ---------------- Fallback: fully fused, no workspace ------------------------
__global__ __launch_bounds__(256) void fused_kernel(
    const float* __restrict__ tvec, const float* __restrict__ offset,
    const float* __restrict__ trend, const float* __restrict__ emd,
    const int* __restrict__ idx, const float* __restrict__ nw,
    const float* __restrict__ lw, const float* __restrict__ amps,
    const float* __restrict__ phases, const float* __restrict__ periods,
    const float* __restrict__ esw, const float* __restrict__ lsw,
    float* __restrict__ out) {
  int n = blockIdx.x;
  int tid = threadIdx.x;
  __shared__ int sidx[K_];
  __shared__ float snw[K_], slw[K_];
  __shared__ float samp[NC_], sph[NC_], somega[NC_];
  __shared__ float s_off, s_tr, s_ew, s_lw;
  if (tid < K_) {
    sidx[tid] = idx[n * K_ + tid];
    snw[tid] = nw[n * K_ + tid];
    slw[tid] = lw[n * K_ + tid];
  }
  __syncthreads();
  if (tid < NC_) {
    int c = tid;
    float asum = 0.f, ssum = 0.f, csum = 0.f;
    for (int k = 0; k < K_; k++) {
      int j = sidx[k];
      float w = snw[k];
      asum += w * amps[j * NC_ + c];
      float p = phases[j * NC_ + c];
      ssum += w * __sinf(p);
      csum += w * __cosf(p);
    }
    samp[c] = (1.f - SMOOTH_F) * amps[n * NC_ + c] + SMOOTH_F * asum;
    sph[c] = (1.f - SMOOTH_F) * phases[n * NC_ + c] + SMOOTH_F * atan2f(ssum, csum);
    float per = fminf(fmaxf(periods[c], 15.f), 350.f);
    somega[c] = TWO_PI_F / per;
  } else if (tid == 64) {
    s_off = offset[n];
    s_tr = trend[n];
    s_ew = 1.f / (1.f + __expf(-esw[n]));
    s_lw = 1.f / (1.f + __expf(-lsw[n]));
  }
  __syncthreads();
  float ew = s_ew, lww = s_lw;
  for (int t = tid; t < T_; t += 256) {
    const float* rown = emd + (size_t)n * 4 * T_ + t;
    float own = rown[0] + rown[T_] + rown[2 * T_] + rown[3 * T_];
    float lsum = 0.f, rsum = 0.f;
#pragma unroll
    for (int k = 0; k < K_; k++) {
      const float* rk = emd + (size_t)sidx[k] * 4 * T_ + t;
      float v = rk[0] + rk[T_] + rk[2 * T_] + rk[3 * T_];
      lsum += slw[k] * v;
      rsum += snw[k] * v;
    }
    float adjusted = (1.f - ew) * own + ew * lww * lsum + ew * (1.f - lww) * rsum;
    float tf = tvec[t];
    float res = 0.f;
#pragma unroll
    for (int c = 0; c < NC_; c++) res += samp[c] * __sinf(somega[c] * tf + sph[c]);
    out[(size_t)n * T_ + t] = s_off + s_tr * tf + adjusted + res;
  }
}

extern "C" void kernel_launch(void* const* d_in, const int* in_sizes, int n_in,
                              void* d_out, int out_size, void* d_ws, size_t ws_size,
                              hipStream_t stream) {
  const float* tvec    = (const float*)d_in[0];
  const float* offset  = (const float*)d_in[1];
  const float* trend   = (const float*)d_in[2];
  const float* emd     = (const float*)d_in[3];
  const int*   idx     = (const int*)d_in[4];
  const float* nw      = (const float*)d_in[5];
  const float* lw      = (const float*)d_in[6];
  const float* amps    = (const float*)d_in[7];
  const float* phases  = (const float*)d_in[8];
  const float* periods = (const float*)d_in[9];
  const float* esw     = (const float*)d_in[10];
  const float* lsw     = (const float*)d_in[11];
  float* out = (float*)d_out;

  const size_t emd_sig_bytes = (size_t)N_ * T_ * sizeof(float);   // 48 MB
  const size_t par_bytes = (size_t)N_ * NC_ * sizeof(float);      // 600 KB
  const size_t need = emd_sig_bytes + 2 * par_bytes;

  if (ws_size >= need) {
    float* emd_sig = (float*)d_ws;
    float* amp_s = (float*)((char*)d_ws + emd_sig_bytes);
    float* ph_s = (float*)((char*)d_ws + emd_sig_bytes + par_bytes);

    int totA = N_ * (T_ / 4);
    emd_sum_kernel<<<(totA + 255) / 256, 256, 0, stream>>>(emd, emd_sig);
    params_kernel<<<(N_ + 255) / 256, 256, 0, stream>>>(idx, nw, amps, phases,
                                                        amp_s, ph_s);
    main_kernel<<<N_, 256, 0, stream>>>(emd_sig, tvec, idx, nw, lw, offset,
                                        trend, esw, lsw, amp_s, ph_s, periods,
                                        out);
  } else {
    fused_kernel<<<N_, 256, 0, stream>>>(tvec, offset, trend, emd, idx, nw, lw,
                                         amps, phases, periods, esw, lsw, out);
  }
}

// Round 3
// 402.265 us; speedup vs baseline: 1.1004x; 1.1004x over previous
//
#include <hip/hip_runtime.h>
#include <math.h>

#define N_ 30000
#define K_ 15
#define T_ 400
#define NC_ 5
#define TQ (T_ / 4)   // 100 float4 per row

typedef float f4 __attribute__((ext_vector_type(4)));   // native vector type

static constexpr float TWO_PI_F = 6.283185307179586f;
static constexpr float SMOOTH_F = 0.2f;

// ---------------- Pass A: emd_signals[n][t] = sum_c emd_seasonal[n][c][t] ----
__global__ __launch_bounds__(256) void emd_sum_kernel(
    const float* __restrict__ emd, float* __restrict__ out) {
  int g = blockIdx.x * blockDim.x + threadIdx.x;          // over N_*TQ
  if (g >= N_ * TQ) return;
  int n = g / TQ;
  int j = g - n * TQ;
  const f4* row = (const f4*)(emd + (size_t)n * 4 * T_);
  f4 a = __builtin_nontemporal_load(&row[j]);
  f4 b = __builtin_nontemporal_load(&row[j + TQ]);
  f4 c = __builtin_nontemporal_load(&row[j + 2 * TQ]);
  f4 d = __builtin_nontemporal_load(&row[j + 3 * TQ]);
  ((f4*)out)[g] = a + b + c + d;   // cached store: gathered by pass C
}

// ---------------- Pass B: smoothed params, one (n,c) per thread --------------
__global__ __launch_bounds__(256) void params_kernel(
    const int* __restrict__ idx, const float* __restrict__ nw,
    const float* __restrict__ amps, const float* __restrict__ phases,
    const float* __restrict__ esw, const float* __restrict__ lsw,
    float* __restrict__ amp_s, float* __restrict__ ph_s,
    float* __restrict__ ew_out, float* __restrict__ lwb_out) {
  int g = blockIdx.x * blockDim.x + threadIdx.x;          // over N_*NC_
  if (g >= N_ * NC_) return;
  int n = g / NC_;
  int c = g - n * NC_;
  float asum = 0.f, ssum = 0.f, csum = 0.f;
#pragma unroll
  for (int k = 0; k < K_; k++) {
    int id = idx[n * K_ + k];
    float w = nw[n * K_ + k];
    asum += w * amps[id * NC_ + c];
    float p = phases[id * NC_ + c];
    ssum += w * __sinf(p);
    csum += w * __cosf(p);
  }
  amp_s[g] = (1.f - SMOOTH_F) * amps[g] + SMOOTH_F * asum;
  ph_s[g] = (1.f - SMOOTH_F) * phases[g] + SMOOTH_F * atan2f(ssum, csum);
  if (c == 0) {
    ew_out[n] = 1.f / (1.f + __expf(-esw[n]));
    lwb_out[n] = 1.f / (1.f + __expf(-lsw[n]));
  }
}

// ---------------- Pass C: float4 gather + blend + residual harmonics ---------
__global__ __launch_bounds__(256) void main_kernel(
    const f4* __restrict__ emd_sig4, const f4* __restrict__ tvec4,
    const int* __restrict__ idx, const float* __restrict__ nw,
    const float* __restrict__ lw, const float* __restrict__ offset,
    const float* __restrict__ trend, const float* __restrict__ ew_arr,
    const float* __restrict__ lwb_arr, const float* __restrict__ amp_s,
    const float* __restrict__ ph_s, const float* __restrict__ periods,
    f4* __restrict__ out4) {
  int g = blockIdx.x * blockDim.x + threadIdx.x;          // over N_*TQ
  if (g >= N_ * TQ) return;
  int n = g / TQ;
  int j = g - n * TQ;
  const int base = n * K_;

  f4 lsum = {0.f, 0.f, 0.f, 0.f};
  f4 rsum = {0.f, 0.f, 0.f, 0.f};
#pragma unroll
  for (int k = 0; k < K_; k++) {
    int id = idx[base + k];
    float wl = lw[base + k];
    float wr = nw[base + k];
    f4 v = emd_sig4[id * TQ + j];
    lsum += wl * v;
    rsum += wr * v;
  }
  f4 own = emd_sig4[n * TQ + j];
  float ew = ew_arr[n];
  float lwb = lwb_arr[n];
  float c_own = 1.f - ew;
  float c_l = ew * lwb;
  float c_r = ew * (1.f - lwb);

  float amp[NC_], ph[NC_], omg[NC_];
#pragma unroll
  for (int c = 0; c < NC_; c++) {
    amp[c] = amp_s[n * NC_ + c];
    ph[c] = ph_s[n * NC_ + c];
    float per = fminf(fmaxf(periods[c], 15.f), 350.f);
    omg[c] = TWO_PI_F / per;
  }

  f4 tf = tvec4[j];
  float off = offset[n];
  float tr = trend[n];

  f4 r = off + tr * tf + c_own * own + c_l * lsum + c_r * rsum;
#pragma unroll
  for (int c = 0; c < NC_; c++) {
    r.x += amp[c] * __sinf(omg[c] * tf.x + ph[c]);
    r.y += amp[c] * __sinf(omg[c] * tf.y + ph[c]);
    r.z += amp[c] * __sinf(omg[c] * tf.z + ph[c]);
    r.w += amp[c] * __sinf(omg[c] * tf.w + ph[c]);
  }
  __builtin_nontemporal_store(r, &out4[g]);
}

// ---------------- Fallback: fully fused, no workspace ------------------------
__global__ __launch_bounds__(256) void fused_kernel(
    const float* __restrict__ tvec, const float* __restrict__ offset,
    const float* __restrict__ trend, const float* __restrict__ emd,
    const int* __restrict__ idx, const float* __restrict__ nw,
    const float* __restrict__ lw, const float* __restrict__ amps,
    const float* __restrict__ phases, const float* __restrict__ periods,
    const float* __restrict__ esw, const float* __restrict__ lsw,
    float* __restrict__ out) {
  int n = blockIdx.x;
  int tid = threadIdx.x;
  __shared__ int sidx[K_];
  __shared__ float snw[K_], slw[K_];
  __shared__ float samp[NC_], sph[NC_], somega[NC_];
  __shared__ float s_off, s_tr, s_ew, s_lw;
  if (tid < K_) {
    sidx[tid] = idx[n * K_ + tid];
    snw[tid] = nw[n * K_ + tid];
    slw[tid] = lw[n * K_ + tid];
  }
  __syncthreads();
  if (tid < NC_) {
    int c = tid;
    float asum = 0.f, ssum = 0.f, csum = 0.f;
    for (int k = 0; k < K_; k++) {
      int j = sidx[k];
      float w = snw[k];
      asum += w * amps[j * NC_ + c];
      float p = phases[j * NC_ + c];
      ssum += w * __sinf(p);
      csum += w * __cosf(p);
    }
    samp[c] = (1.f - SMOOTH_F) * amps[n * NC_ + c] + SMOOTH_F * asum;
    sph[c] = (1.f - SMOOTH_F) * phases[n * NC_ + c] + SMOOTH_F * atan2f(ssum, csum);
    float per = fminf(fmaxf(periods[c], 15.f), 350.f);
    somega[c] = TWO_PI_F / per;
  } else if (tid == 64) {
    s_off = offset[n];
    s_tr = trend[n];
    s_ew = 1.f / (1.f + __expf(-esw[n]));
    s_lw = 1.f / (1.f + __expf(-lsw[n]));
  }
  __syncthreads();
  float ew = s_ew, lww = s_lw;
  for (int t = tid; t < T_; t += 256) {
    const float* rown = emd + (size_t)n * 4 * T_ + t;
    float own = rown[0] + rown[T_] + rown[2 * T_] + rown[3 * T_];
    float lsum = 0.f, rsum = 0.f;
#pragma unroll
    for (int k = 0; k < K_; k++) {
      const float* rk = emd + (size_t)sidx[k] * 4 * T_ + t;
      float v = rk[0] + rk[T_] + rk[2 * T_] + rk[3 * T_];
      lsum += slw[k] * v;
      rsum += snw[k] * v;
    }
    float adjusted = (1.f - ew) * own + ew * lww * lsum + ew * (1.f - lww) * rsum;
    float tf = tvec[t];
    float res = 0.f;
#pragma unroll
    for (int c = 0; c < NC_; c++) res += samp[c] * __sinf(somega[c] * tf + sph[c]);
    out[(size_t)n * T_ + t] = s_off + s_tr * tf + adjusted + res;
  }
}

extern "C" void kernel_launch(void* const* d_in, const int* in_sizes, int n_in,
                              void* d_out, int out_size, void* d_ws, size_t ws_size,
                              hipStream_t stream) {
  const float* tvec    = (const float*)d_in[0];
  const float* offset  = (const float*)d_in[1];
  const float* trend   = (const float*)d_in[2];
  const float* emd     = (const float*)d_in[3];
  const int*   idx     = (const int*)d_in[4];
  const float* nw      = (const float*)d_in[5];
  const float* lw      = (const float*)d_in[6];
  const float* amps    = (const float*)d_in[7];
  const float* phases  = (const float*)d_in[8];
  const float* periods = (const float*)d_in[9];
  const float* esw     = (const float*)d_in[10];
  const float* lsw     = (const float*)d_in[11];
  float* out = (float*)d_out;

  const size_t emd_sig_bytes = (size_t)N_ * T_ * sizeof(float);   // 48 MB
  const size_t par_bytes = (size_t)N_ * NC_ * sizeof(float);      // 600 KB
  const size_t n_bytes = (size_t)N_ * sizeof(float);              // 120 KB
  const size_t need = emd_sig_bytes + 2 * par_bytes + 2 * n_bytes;

  if (ws_size >= need) {
    char* p = (char*)d_ws;
    float* emd_sig = (float*)p;           p += emd_sig_bytes;
    float* amp_s   = (float*)p;           p += par_bytes;
    float* ph_s    = (float*)p;           p += par_bytes;
    float* ew_arr  = (float*)p;           p += n_bytes;
    float* lwb_arr = (float*)p;           p += n_bytes;

    int totA = N_ * TQ;
    emd_sum_kernel<<<(totA + 255) / 256, 256, 0, stream>>>(emd, emd_sig);
    params_kernel<<<(N_ * NC_ + 255) / 256, 256, 0, stream>>>(
        idx, nw, amps, phases, esw, lsw, amp_s, ph_s, ew_arr, lwb_arr);
    main_kernel<<<(totA + 255) / 256, 256, 0, stream>>>(
        (const f4*)emd_sig, (const f4*)tvec, idx, nw, lw, offset,
        trend, ew_arr, lwb_arr, amp_s, ph_s, periods, (f4*)out);
  } else {
    fused_kernel<<<N_, 256, 0, stream>>>(tvec, offset, trend, emd, idx, nw, lw,
                                         amps, phases, periods, esw, lsw, out);
  }
}

// Round 4
// 354.020 us; speedup vs baseline: 1.2503x; 1.1363x over previous
//
#include <hip/hip_runtime.h>
#include <math.h>

#define N_ 30000
#define K_ 15
#define T_ 400
#define NC_ 5
#define TQ (T_ / 4)   // 100 float4 per row
#define TH (T_ / 8)   // 50 half8 per row

typedef float f4 __attribute__((ext_vector_type(4)));
typedef _Float16 h4 __attribute__((ext_vector_type(4)));
typedef _Float16 h8 __attribute__((ext_vector_type(8)));

static constexpr float TWO_PI_F = 6.283185307179586f;
static constexpr float SMOOTH_F = 0.2f;

// ---- Pass A: emd_sig_h[n][t] = (fp16) sum_c emd_seasonal[n][c][t] ----------
__global__ __launch_bounds__(256) void emd_sum_kernel(
    const float* __restrict__ emd, _Float16* __restrict__ out_h) {
  int g = blockIdx.x * blockDim.x + threadIdx.x;          // over N_*TQ
  if (g >= N_ * TQ) return;
  int n = g / TQ;
  int j = g - n * TQ;
  const f4* row = (const f4*)(emd + (size_t)n * 4 * T_);
  f4 a = __builtin_nontemporal_load(&row[j]);
  f4 b = __builtin_nontemporal_load(&row[j + TQ]);
  f4 c = __builtin_nontemporal_load(&row[j + 2 * TQ]);
  f4 d = __builtin_nontemporal_load(&row[j + 3 * TQ]);
  f4 s = a + b + c + d;
  h4 o = {(_Float16)s.x, (_Float16)s.y, (_Float16)s.z, (_Float16)s.w};
  ((h4*)out_h)[g] = o;   // cached: gathered by pass C
}

// ---- Pass B1: smoothed residual params, one (n,c) per thread ---------------
__global__ __launch_bounds__(256) void params_kernel(
    const int* __restrict__ idx, const float* __restrict__ nw,
    const float* __restrict__ amps, const float* __restrict__ phases,
    float* __restrict__ amp_s, float* __restrict__ ph_s) {
  int g = blockIdx.x * blockDim.x + threadIdx.x;          // over N_*NC_
  if (g >= N_ * NC_) return;
  int n = g / NC_;
  int c = g - n * NC_;
  float asum = 0.f, ssum = 0.f, csum = 0.f;
#pragma unroll
  for (int k = 0; k < K_; k++) {
    int id = idx[n * K_ + k];
    float w = nw[n * K_ + k];
    asum += w * amps[id * NC_ + c];
    float p = phases[id * NC_ + c];
    ssum += w * __sinf(p);
    csum += w * __cosf(p);
  }
  amp_s[g] = (1.f - SMOOTH_F) * amps[g] + SMOOTH_F * asum;
  ph_s[g] = (1.f - SMOOTH_F) * phases[g] + SMOOTH_F * atan2f(ssum, csum);
}

// ---- Pass B2: combined gather weights, one (n,k) per thread ----------------
__global__ __launch_bounds__(256) void cw_kernel(
    const float* __restrict__ nw, const float* __restrict__ lw,
    const float* __restrict__ esw, const float* __restrict__ lsw,
    float* __restrict__ cw, float* __restrict__ c_own) {
  int g = blockIdx.x * blockDim.x + threadIdx.x;          // over N_*K_
  if (g >= N_ * K_) return;
  int n = g / K_;
  float ew = 1.f / (1.f + __expf(-esw[n]));
  float lwb = 1.f / (1.f + __expf(-lsw[n]));
  cw[g] = ew * (lwb * lw[g] + (1.f - lwb) * nw[g]);
  if (g - n * K_ == 0) c_own[n] = 1.f - ew;
}

// ---- Pass C: fp16 gather + blend + residual harmonics, 8 outputs/thread ----
__global__ __launch_bounds__(256) void main_kernel(
    const h8* __restrict__ emd_h8, const f4* __restrict__ tvec4,
    const int* __restrict__ idx, const float* __restrict__ cw,
    const float* __restrict__ c_own, const float* __restrict__ offset,
    const float* __restrict__ trend, const float* __restrict__ amp_s,
    const float* __restrict__ ph_s, const float* __restrict__ periods,
    f4* __restrict__ out4) {
  int g = blockIdx.x * blockDim.x + threadIdx.x;          // over N_*TH
  if (g >= N_ * TH) return;
  int n = g / TH;
  int j = g - n * TH;
  const int base = n * K_;

  float acc[8] = {0.f, 0.f, 0.f, 0.f, 0.f, 0.f, 0.f, 0.f};
#pragma unroll
  for (int k = 0; k < K_; k++) {
    int id = idx[base + k];
    float w = cw[base + k];
    h8 v = emd_h8[(size_t)id * TH + j];
#pragma unroll
    for (int i = 0; i < 8; i++) acc[i] += w * (float)v[i];
  }
  h8 own = emd_h8[(size_t)n * TH + j];
  float co = c_own[n];
  float off = offset[n];
  float tr = trend[n];

  float amp[NC_], ph[NC_], omg[NC_];
#pragma unroll
  for (int c = 0; c < NC_; c++) {
    amp[c] = amp_s[n * NC_ + c];
    ph[c] = ph_s[n * NC_ + c];
    float per = fminf(fmaxf(periods[c], 15.f), 350.f);
    omg[c] = TWO_PI_F / per;
  }

  f4 tf0 = tvec4[2 * j];
  f4 tf1 = tvec4[2 * j + 1];
  float t8[8] = {tf0.x, tf0.y, tf0.z, tf0.w, tf1.x, tf1.y, tf1.z, tf1.w};

  float r8[8];
#pragma unroll
  for (int i = 0; i < 8; i++) {
    float r = off + tr * t8[i] + co * (float)own[i] + acc[i];
#pragma unroll
    for (int c = 0; c < NC_; c++) r += amp[c] * __sinf(omg[c] * t8[i] + ph[c]);
    r8[i] = r;
  }
  f4 o0 = {r8[0], r8[1], r8[2], r8[3]};
  f4 o1 = {r8[4], r8[5], r8[6], r8[7]};
  __builtin_nontemporal_store(o0, &out4[2 * g]);
  __builtin_nontemporal_store(o1, &out4[2 * g + 1]);
}

// ---- Fallback: fully fused, no workspace -----------------------------------
__global__ __launch_bounds__(256) void fused_kernel(
    const float* __restrict__ tvec, const float* __restrict__ offset,
    const float* __restrict__ trend, const float* __restrict__ emd,
    const int* __restrict__ idx, const float* __restrict__ nw,
    const float* __restrict__ lw, const float* __restrict__ amps,
    const float* __restrict__ phases, const float* __restrict__ periods,
    const float* __restrict__ esw, const float* __restrict__ lsw,
    float* __restrict__ out) {
  int n = blockIdx.x;
  int tid = threadIdx.x;
  __shared__ int sidx[K_];
  __shared__ float snw[K_], slw[K_];
  __shared__ float samp[NC_], sph[NC_], somega[NC_];
  __shared__ float s_off, s_tr, s_ew, s_lw;
  if (tid < K_) {
    sidx[tid] = idx[n * K_ + tid];
    snw[tid] = nw[n * K_ + tid];
    slw[tid] = lw[n * K_ + tid];
  }
  __syncthreads();
  if (tid < NC_) {
    int c = tid;
    float asum = 0.f, ssum = 0.f, csum = 0.f;
    for (int k = 0; k < K_; k++) {
      int j = sidx[k];
      float w = snw[k];
      asum += w * amps[j * NC_ + c];
      float p = phases[j * NC_ + c];
      ssum += w * __sinf(p);
      csum += w * __cosf(p);
    }
    samp[c] = (1.f - SMOOTH_F) * amps[n * NC_ + c] + SMOOTH_F * asum;
    sph[c] = (1.f - SMOOTH_F) * phases[n * NC_ + c] + SMOOTH_F * atan2f(ssum, csum);
    float per = fminf(fmaxf(periods[c], 15.f), 350.f);
    somega[c] = TWO_PI_F / per;
  } else if (tid == 64) {
    s_off = offset[n];
    s_tr = trend[n];
    s_ew = 1.f / (1.f + __expf(-esw[n]));
    s_lw = 1.f / (1.f + __expf(-lsw[n]));
  }
  __syncthreads();
  float ew = s_ew, lww = s_lw;
  for (int t = tid; t < T_; t += 256) {
    const float* rown = emd + (size_t)n * 4 * T_ + t;
    float own = rown[0] + rown[T_] + rown[2 * T_] + rown[3 * T_];
    float lsum = 0.f, rsum = 0.f;
#pragma unroll
    for (int k = 0; k < K_; k++) {
      const float* rk = emd + (size_t)sidx[k] * 4 * T_ + t;
      float v = rk[0] + rk[T_] + rk[2 * T_] + rk[3 * T_];
      lsum += slw[k] * v;
      rsum += snw[k] * v;
    }
    float adjusted = (1.f - ew) * own + ew * lww * lsum + ew * (1.f - lww) * rsum;
    float tf = tvec[t];
    float res = 0.f;
#pragma unroll
    for (int c = 0; c < NC_; c++) res += samp[c] * __sinf(somega[c] * tf + sph[c]);
    out[(size_t)n * T_ + t] = s_off + s_tr * tf + adjusted + res;
  }
}

extern "C" void kernel_launch(void* const* d_in, const int* in_sizes, int n_in,
                              void* d_out, int out_size, void* d_ws, size_t ws_size,
                              hipStream_t stream) {
  const float* tvec    = (const float*)d_in[0];
  const float* offset  = (const float*)d_in[1];
  const float* trend   = (const float*)d_in[2];
  const float* emd     = (const float*)d_in[3];
  const int*   idx     = (const int*)d_in[4];
  const float* nw      = (const float*)d_in[5];
  const float* lw      = (const float*)d_in[6];
  const float* amps    = (const float*)d_in[7];
  const float* phases  = (const float*)d_in[8];
  const float* periods = (const float*)d_in[9];
  const float* esw     = (const float*)d_in[10];
  const float* lsw     = (const float*)d_in[11];
  float* out = (float*)d_out;

  const size_t emd_h_bytes = (size_t)N_ * T_ * sizeof(_Float16);  // 24 MB
  const size_t par_bytes = (size_t)N_ * NC_ * sizeof(float);      // 600 KB
  const size_t cw_bytes = (size_t)N_ * K_ * sizeof(float);        // 1.8 MB
  const size_t n_bytes = (size_t)N_ * sizeof(float);              // 120 KB
  const size_t need = emd_h_bytes + 2 * par_bytes + cw_bytes + n_bytes;

  if (ws_size >= need) {
    char* p = (char*)d_ws;
    _Float16* emd_h = (_Float16*)p;       p += emd_h_bytes;
    float* amp_s    = (float*)p;          p += par_bytes;
    float* ph_s     = (float*)p;          p += par_bytes;
    float* cw       = (float*)p;          p += cw_bytes;
    float* c_own    = (float*)p;          p += n_bytes;

    emd_sum_kernel<<<(N_ * TQ + 255) / 256, 256, 0, stream>>>(emd, emd_h);
    params_kernel<<<(N_ * NC_ + 255) / 256, 256, 0, stream>>>(
        idx, nw, amps, phases, amp_s, ph_s);
    cw_kernel<<<(N_ * K_ + 255) / 256, 256, 0, stream>>>(
        nw, lw, esw, lsw, cw, c_own);
    main_kernel<<<(N_ * TH + 255) / 256, 256, 0, stream>>>(
        (const h8*)emd_h, (const f4*)tvec, idx, cw, c_own, offset, trend,
        amp_s, ph_s, periods, (f4*)out);
  } else {
    fused_kernel<<<N_, 256, 0, stream>>>(tvec, offset, trend, emd, idx, nw, lw,
                                         amps, phases, periods, esw, lsw, out);
  }
}